// Round 8
// baseline (124.167 us; speedup 1.0000x reference)
//
#include <hip/hip_runtime.h>

// GCNConv: out = D^-1/2 (A + I) D^-1/2 (x W) + bias
// N = 10000, E = 640000, D_IN = D_OUT = 128, fp32 in/out.
//
// Round 15: NB 64 -> 128. Hist is the long pole and runs on only
// 2 blocks/CU (60 KB LDS); at NB=64 that's 32 CUs busy while 224 idle.
// NB=128 halves per-block edge passes (5000 edges) and doubles hist CU
// coverage. (R11's NB=256 regression was the OLD structure's strided
// reduce kernel + 4x partial traffic -- both gone since R13: scan is
// in-LDS, meta cost is only +2.56 MB.)
// Structure (R13/R14-verified): memset(outdeg) -> K1 histsort||gemm -> K2.
//   K1 blocks 0..127: LDS packed histogram -> in-LDS prefix scan ->
//     meta[c*128+b] = loff|cnt<<16, atomicAdd outdeg (fire-and-forget),
//     bump-scatter src ids into block-private CSR (blkcsr[b*EPB + slot]).
//   K1 blocks 128..440: g = bf16(x @ W) UNSCALED.
//   K2: wave/node c; lane l owns segments l AND l+64; 2 coalesced meta
//     loads, merged wave-scan -> flat LDS stage of (src, ds); consume
//     4 edges/step, 16 lanes x 16B per row;
//     out = dc*(sum + dc*g[c]) + bias.   (R10/R12/R13-verified numerics)

#define NNODES 10000
#define NB 128           // hist blocks == CSR buckets (2 segments/lane)
#define HBLOCK 1024
#define STAGE_CAP 256    // max indeg staged per wave (obs max ~110)

__device__ inline unsigned short f2bf(float f) {
    union { float f; unsigned u; } v; v.f = f;
    unsigned r = v.u + 0x7FFFu + ((v.u >> 16) & 1u);   // RNE
    return (unsigned short)(r >> 16);
}
__device__ inline float bf2f_lo(unsigned u) {   // low ushort of dword -> f32
    union { unsigned u; float f; } v; v.u = u << 16; return v.f;
}
__device__ inline float bf2f_hi(unsigned u) {   // high ushort of dword -> f32
    union { unsigned u; float f; } v; v.u = u & 0xFFFF0000u; return v.f;
}

// ---- K1: blocks 0..NB-1 hist-sort; blocks NB.. gemm (unscaled bf16) ----
__global__ __launch_bounds__(HBLOCK) void histsort_gemm_kernel(
    const int* __restrict__ row, const int* __restrict__ col,
    const float* __restrict__ x, const float* __restrict__ W,
    unsigned* __restrict__ meta, int* __restrict__ outdeg,
    unsigned short* __restrict__ blkcsr, unsigned short* __restrict__ g,
    int N, int E, int EPB) {
    __shared__ int hmem[NNODES];              // 40 KB (gemm: reused as x-tile)
    __shared__ unsigned short loff16[NNODES]; // 20 KB
    __shared__ int wsum[16];
    const int tid = threadIdx.x;

    if (blockIdx.x < NB) {
        const int b = blockIdx.x;
        for (int j = tid; j < NNODES; j += HBLOCK) hmem[j] = 0;
        __syncthreads();
        const int e0 = b * EPB, e1 = min(E, e0 + EPB);
        const int span = e1 - e0;
        // int4 path valid when both sub-array bases are 16B aligned
        const bool vec4 = ((((size_t)(row + e0)) | ((size_t)(col + e0))) & 15) == 0;
        const int nq = vec4 ? (span >> 2) : 0;
        const int4* __restrict__ r4p = (const int4*)(row + e0);
        const int4* __restrict__ c4p = (const int4*)(col + e0);
        // pass1: packed counts (no atomic-return needed), 4 edges/thread
        for (int qi = tid; qi < nq; qi += HBLOCK) {
            int4 r4 = r4p[qi], c4 = c4p[qi];
            atomicAdd((unsigned*)&hmem[r4.x], 1u);
            atomicAdd((unsigned*)&hmem[r4.y], 1u);
            atomicAdd((unsigned*)&hmem[r4.z], 1u);
            atomicAdd((unsigned*)&hmem[r4.w], 1u);
            atomicAdd((unsigned*)&hmem[c4.x], 0x10000u);
            atomicAdd((unsigned*)&hmem[c4.y], 0x10000u);
            atomicAdd((unsigned*)&hmem[c4.z], 0x10000u);
            atomicAdd((unsigned*)&hmem[c4.w], 0x10000u);
        }
        for (int e = e0 + nq * 4 + tid; e < e1; e += HBLOCK) {
            atomicAdd((unsigned*)&hmem[row[e]], 1u);
            atomicAdd((unsigned*)&hmem[col[e]], 0x10000u);
        }
        __syncthreads();
        // exclusive prefix scan of in-counts (hmem>>16) into loff16
        {
            const int lane = tid & 63, wid = tid >> 6;
            const int i0 = tid * 10;
            const int i1 = min(NNODES, i0 + 10);       // 1024*10 >= 10000
            int s = 0;
            for (int i = i0; i < i1; ++i) s += (int)(((unsigned)hmem[i]) >> 16);
            int p = s;
#pragma unroll
            for (int d = 1; d < 64; d <<= 1) {
                int y = __shfl_up(p, d);
                if (lane >= d) p += y;
            }
            if (lane == 63) wsum[wid] = p;
            __syncthreads();
            if (tid < 16) {
                int v = wsum[tid];
#pragma unroll
                for (int d = 1; d < 16; d <<= 1) {
                    int y = __shfl_up(v, d);
                    if (tid >= d) v += y;
                }
                wsum[tid] = v;
            }
            __syncthreads();
            int run = (wid ? wsum[wid - 1] : 0) + (p - s);   // thread-exclusive
            for (int i = i0; i < i1; ++i) {
                loff16[i] = (unsigned short)run;
                run += (int)(((unsigned)hmem[i]) >> 16);
            }
        }
        __syncthreads();
        // writeback meta + outdeg; init bump pointers
        for (int j = tid; j < NNODES; j += HBLOCK) {
            unsigned v = (unsigned)hmem[j];
            unsigned cnt = v >> 16;
            unsigned lo = (unsigned)loff16[j];
            meta[(size_t)j * NB + b] = lo | (cnt << 16);
            int od = (int)(v & 0xFFFFu);
            if (od) atomicAdd(&outdeg[j], od);
            hmem[j] = (int)lo;
        }
        __syncthreads();
        // pass2: bump-scatter src ids into block-private CSR region
        unsigned short* __restrict__ bc = blkcsr + (size_t)b * EPB;
        for (int qi = tid; qi < nq; qi += HBLOCK) {
            int4 r4 = r4p[qi], c4 = c4p[qi];
            int s0 = atomicAdd(&hmem[c4.x], 1);
            bc[s0] = (unsigned short)r4.x;
            int s1 = atomicAdd(&hmem[c4.y], 1);
            bc[s1] = (unsigned short)r4.y;
            int s2 = atomicAdd(&hmem[c4.z], 1);
            bc[s2] = (unsigned short)r4.z;
            int s3 = atomicAdd(&hmem[c4.w], 1);
            bc[s3] = (unsigned short)r4.w;
        }
        for (int e = e0 + nq * 4 + tid; e < e1; e += HBLOCK) {
            int slot = atomicAdd(&hmem[col[e]], 1);
            bc[slot] = (unsigned short)row[e];
        }
    } else {
        // ---- gemm: g = bf16(x @ W) unscaled; 32 rows/block ----
        float* xs = (float*)hmem;                       // 16 KB of the 40
        const int rowBase = (blockIdx.x - NB) * 32;
        {
            int r = rowBase + (tid >> 5);
            float4 v = make_float4(0.f, 0.f, 0.f, 0.f);
            if (r < N) v = ((const float4*)x)[rowBase * 32 + tid];
            ((float4*)xs)[tid] = v;
        }
        __syncthreads();
        const int lr = tid >> 5, c4 = tid & 31;
        const int rr = rowBase + lr;
        const float4* __restrict__ W4 = (const float4*)W;
        float4 acc = make_float4(0.f, 0.f, 0.f, 0.f);
#pragma unroll 8
        for (int k = 0; k < 128; ++k) {
            float xv = xs[lr * 128 + k];
            float4 wv = W4[k * 32 + c4];
            acc.x = fmaf(xv, wv.x, acc.x);
            acc.y = fmaf(xv, wv.y, acc.y);
            acc.z = fmaf(xv, wv.z, acc.z);
            acc.w = fmaf(xv, wv.w, acc.w);
        }
        if (rr < N) {
            ushort4 o;
            o.x = f2bf(acc.x);
            o.y = f2bf(acc.y);
            o.z = f2bf(acc.z);
            o.w = f2bf(acc.w);
            ((ushort4*)g)[rr * 32 + c4] = o;
        }
    }
}

// ---- K2: gather. Wave per node; lane l owns segments l and l+64. ----
__global__ __launch_bounds__(256) void gather_kernel(
    const int* __restrict__ outdeg, const unsigned* __restrict__ meta,
    const unsigned short* __restrict__ blkcsr,
    const unsigned short* __restrict__ g, const float* __restrict__ bias,
    float* __restrict__ out, int N, int EPB) {
    __shared__ unsigned short stage[4][STAGE_CAP];
    __shared__ float dstage[4][STAGE_CAP];
    const int wv = threadIdx.x >> 6;
    const int lane = threadIdx.x & 63;
    const int c = (int)((blockIdx.x * blockDim.x + threadIdx.x) >> 6);
    const bool act = (c < N);

    // meta for this node: two coalesced uint loads across the wave
    unsigned m0 = act ? meta[(size_t)c * NB + lane] : 0u;
    unsigned m1 = act ? meta[(size_t)c * NB + 64 + lane] : 0u;
    int sl0 = (int)(m0 & 0xFFFFu), cn0 = (int)(m0 >> 16);
    int sl1 = (int)(m1 & 0xFFFFu), cn1 = (int)(m1 >> 16);
    int cn = cn0 + cn1;
    // wave-exclusive prefix of merged segment counts -> flat position
    int p = cn;
#pragma unroll
    for (int d = 1; d < 64; d <<= 1) {
        int y = __shfl_up(p, d);
        if (lane >= d) p += y;
    }
    int excl = p - cn;
    int L = __shfl(p, 63);              // total indeg of node c
    // stage own segments (src id + ds) into the wave's flat LDS lists;
    // ds computed ONCE per edge at staging time.
    if (act && cn) {
        int kk = excl;
        const unsigned short* seg0 = blkcsr + (size_t)lane * EPB + sl0;
        for (int k = 0; k < cn0; ++k, ++kk) {
            int r = (int)seg0[k];
            stage[wv][kk] = (unsigned short)r;
            dstage[wv][kk] = rsqrtf(1.0f + (float)outdeg[r]);
        }
        const unsigned short* seg1 = blkcsr + (size_t)(lane + 64) * EPB + sl1;
        for (int k = 0; k < cn1; ++k, ++kk) {
            int r = (int)seg1[k];
            stage[wv][kk] = (unsigned short)r;
            dstage[wv][kk] = rsqrtf(1.0f + (float)outdeg[r]);
        }
    }
    __syncthreads();                     // arrival + LDS ordering
    if (!act) return;

    const int q = lane >> 4;             // edge sub-slot within a 4-edge step
    const int l16 = lane & 15;           // 16B chunk within the 256B row
    const uint4* __restrict__ g4 = (const uint4*)g;
    const float dc = rsqrtf(1.0f + (float)outdeg[c]);

    float al0 = 0.f, ah0 = 0.f, al1 = 0.f, ah1 = 0.f;
    float al2 = 0.f, ah2 = 0.f, al3 = 0.f, ah3 = 0.f;

    if (q == 0) {   // self-loop term: dis[c] * g[c] (counted once)
        uint4 w = g4[(size_t)c * 16 + l16];
        al0 = fmaf(bf2f_lo(w.x), dc, al0); ah0 = fmaf(bf2f_hi(w.x), dc, ah0);
        al1 = fmaf(bf2f_lo(w.y), dc, al1); ah1 = fmaf(bf2f_hi(w.y), dc, ah1);
        al2 = fmaf(bf2f_lo(w.z), dc, al2); ah2 = fmaf(bf2f_hi(w.z), dc, ah2);
        al3 = fmaf(bf2f_lo(w.w), dc, al3); ah3 = fmaf(bf2f_hi(w.w), dc, ah3);
    }

    for (int base = 0; base < L; base += 64) {
        int cnt = min(64, L - base);
#pragma unroll
        for (int t = 0; t < 64; t += 4) {
            int j = t + q;               // quarter q handles edge t+q
            if (j < cnt) {
                int r = (int)stage[wv][base + j];   // LDS broadcast
                float ds = dstage[wv][base + j];    // LDS broadcast
                uint4 w = g4[(size_t)r * 16 + l16];
                al0 = fmaf(bf2f_lo(w.x), ds, al0); ah0 = fmaf(bf2f_hi(w.x), ds, ah0);
                al1 = fmaf(bf2f_lo(w.y), ds, al1); ah1 = fmaf(bf2f_hi(w.y), ds, ah1);
                al2 = fmaf(bf2f_lo(w.z), ds, al2); ah2 = fmaf(bf2f_hi(w.z), ds, ah2);
                al3 = fmaf(bf2f_lo(w.w), ds, al3); ah3 = fmaf(bf2f_hi(w.w), ds, ah3);
            }
        }
    }
    // Butterfly over lane bits 5,4: full sums land in every lane.
    al0 += __shfl(al0, lane ^ 32); ah0 += __shfl(ah0, lane ^ 32);
    al1 += __shfl(al1, lane ^ 32); ah1 += __shfl(ah1, lane ^ 32);
    al2 += __shfl(al2, lane ^ 32); ah2 += __shfl(ah2, lane ^ 32);
    al3 += __shfl(al3, lane ^ 32); ah3 += __shfl(ah3, lane ^ 32);
    al0 += __shfl(al0, lane ^ 16); ah0 += __shfl(ah0, lane ^ 16);
    al1 += __shfl(al1, lane ^ 16); ah1 += __shfl(ah1, lane ^ 16);
    al2 += __shfl(al2, lane ^ 16); ah2 += __shfl(ah2, lane ^ 16);
    al3 += __shfl(al3, lane ^ 16); ah3 += __shfl(ah3, lane ^ 16);

    if (lane < 32) {
        // lane l<16 writes cols l*8..l*8+3 (dwords 0,1);
        // lane l+16 writes cols l*8+4..l*8+7 (dwords 2,3).
        int oi = ((lane & 15) << 1) | (lane >> 4);   // float4 slot 0..31
        float4 bv = ((const float4*)bias)[oi];
        float4 o;
        if (lane < 16) {
            o.x = fmaf(al0, dc, bv.x);
            o.y = fmaf(ah0, dc, bv.y);
            o.z = fmaf(al1, dc, bv.z);
            o.w = fmaf(ah1, dc, bv.w);
        } else {
            o.x = fmaf(al2, dc, bv.x);
            o.y = fmaf(ah2, dc, bv.y);
            o.z = fmaf(al3, dc, bv.z);
            o.w = fmaf(ah3, dc, bv.w);
        }
        ((float4*)out)[(size_t)c * 32 + oi] = o;
    }
}

extern "C" void kernel_launch(void* const* d_in, const int* in_sizes, int n_in,
                              void* d_out, int out_size, void* d_ws, size_t ws_size,
                              hipStream_t stream) {
    const float* x    = (const float*)d_in[0];
    const int*   ei   = (const int*)d_in[1];
    const float* W    = (const float*)d_in[2];
    const float* bias = (const float*)d_in[3];
    float* out = (float*)d_out;

    int N = in_sizes[0] / 128;     // 10000
    int E = in_sizes[1] / 2;       // 640000
    const int* row = ei;
    const int* col = ei + E;
    int EPB = (E + NB - 1) / NB;   // 5000

    // Workspace (~9.1 MB):
    auto align256 = [](size_t v) { return (v + 255) & ~(size_t)255; };
    char* p = (char*)d_ws;
    int*            outdeg = (int*)p;            p += align256((size_t)N * 4);           // 40 KB
    unsigned*       meta   = (unsigned*)p;       p += align256((size_t)N * NB * 4);      // 5.12 MB
    unsigned short* blkcsr = (unsigned short*)p; p += align256((size_t)NB * EPB * 2);    // 1.28 MB
    unsigned short* g      = (unsigned short*)p; p += align256((size_t)N * 128 * 2);     // 2.56 MB

    hipMemsetAsync(outdeg, 0, (size_t)N * 4, stream);

    int gemmBlocks = (N + 31) / 32;  // 313
    histsort_gemm_kernel<<<NB + gemmBlocks, HBLOCK, 0, stream>>>(
        row, col, x, W, meta, outdeg, blkcsr, g, N, E, EPB);

    int gBlocks = (N + 3) / 4;       // 4 waves (nodes) per 256-thread block
    gather_kernel<<<gBlocks, 256, 0, stream>>>(
        outdeg, meta, blkcsr, g, bias, out, N, EPB);
}

// Round 9
// 109.094 us; speedup vs baseline: 1.1382x; 1.1382x over previous
//
#include <hip/hip_runtime.h>

// GCNConv: out = D^-1/2 (A + I) D^-1/2 (x W) + bias
// N = 10000, E = 640000, D_IN = D_OUT = 128, fp32 in/out.
//
// Round 16 (NB back to 64; R15's NB=128 regressed):
//  1. GEMM rebuilt for W-L1 reuse: 128-row blocks (79), thread = 4 rows x
//     4 cols, wave = 4 row-groups x 16 col-groups. Per k: ONE ds_read_b128
//     (4 rows of x from a transposed LDS tile [k][row], pad 132) + ONE
//     256B coalesced W float4 load (16 distinct/wave, 4x row-reuse) +
//     16 FMA. W-L1 traffic/block: ~1-2 MB -> 512 KB; blocks 313 -> 79.
//  2. meta now BLOCK-major meta[b*N+j]: hist writes full-line coalesced
//     (kills cross-XCD false sharing of node-major layout); K2 reads it
//     strided (L2-hot, latency hidden by occupancy).
// Structure (R13/R14-verified): memset(outdeg) -> K1 histsort||gemm -> K2.
//   K2: wave/node c; lane l owns block l's segment; wave-scan -> flat LDS
//     stage of (src, ds); consume 4 edges/step, 16 lanes x 16B per row;
//     out = dc*(sum + dc*g[c]) + bias.

#define NNODES 10000
#define NB 64            // hist blocks == CSR buckets == gather lanes
#define HBLOCK 1024
#define STAGE_CAP 256    // max indeg staged per wave (obs max ~110)
#define GROWS 128        // gemm rows per block
#define XPAD 132         // padded row stride (dwords) of transposed x-tile

__device__ inline unsigned short f2bf(float f) {
    union { float f; unsigned u; } v; v.f = f;
    unsigned r = v.u + 0x7FFFu + ((v.u >> 16) & 1u);   // RNE
    return (unsigned short)(r >> 16);
}
__device__ inline float bf2f_lo(unsigned u) {   // low ushort of dword -> f32
    union { unsigned u; float f; } v; v.u = u << 16; return v.f;
}
__device__ inline float bf2f_hi(unsigned u) {   // high ushort of dword -> f32
    union { unsigned u; float f; } v; v.u = u & 0xFFFF0000u; return v.f;
}

// ---- K1: blocks 0..NB-1 hist-sort; blocks NB.. gemm (unscaled bf16) ----
__global__ __launch_bounds__(HBLOCK) void histsort_gemm_kernel(
    const int* __restrict__ row, const int* __restrict__ col,
    const float* __restrict__ x, const float* __restrict__ W,
    unsigned* __restrict__ meta, int* __restrict__ outdeg,
    unsigned short* __restrict__ blkcsr, unsigned short* __restrict__ g,
    int N, int E, int EPB) {
    // union: hist needs 60.1 KB (hmem 40K + loff16 20K + wsum), gemm needs
    // 128*132*4 = 67.6 KB transposed x-tile.
    __shared__ __align__(16) char smem[GROWS * XPAD * 4];
    int* hmem = (int*)smem;                               // [NNODES]
    unsigned short* loff16 = (unsigned short*)(smem + 40000);  // [NNODES]
    int* wsum = (int*)(smem + 60000);                     // [16]
    float* xs = (float*)smem;                             // [128][XPAD]
    const int tid = threadIdx.x;

    if (blockIdx.x < NB) {
        const int b = blockIdx.x;
        for (int j = tid; j < NNODES; j += HBLOCK) hmem[j] = 0;
        __syncthreads();
        const int e0 = b * EPB, e1 = min(E, e0 + EPB);
        const int span = e1 - e0;
        const bool vec4 = ((((size_t)(row + e0)) | ((size_t)(col + e0))) & 15) == 0;
        const int nq = vec4 ? (span >> 2) : 0;
        const int4* __restrict__ r4p = (const int4*)(row + e0);
        const int4* __restrict__ c4p = (const int4*)(col + e0);
        // pass1: packed counts (out lo16 | in hi16)
        for (int qi = tid; qi < nq; qi += HBLOCK) {
            int4 r4 = r4p[qi], c4 = c4p[qi];
            atomicAdd((unsigned*)&hmem[r4.x], 1u);
            atomicAdd((unsigned*)&hmem[r4.y], 1u);
            atomicAdd((unsigned*)&hmem[r4.z], 1u);
            atomicAdd((unsigned*)&hmem[r4.w], 1u);
            atomicAdd((unsigned*)&hmem[c4.x], 0x10000u);
            atomicAdd((unsigned*)&hmem[c4.y], 0x10000u);
            atomicAdd((unsigned*)&hmem[c4.z], 0x10000u);
            atomicAdd((unsigned*)&hmem[c4.w], 0x10000u);
        }
        for (int e = e0 + nq * 4 + tid; e < e1; e += HBLOCK) {
            atomicAdd((unsigned*)&hmem[row[e]], 1u);
            atomicAdd((unsigned*)&hmem[col[e]], 0x10000u);
        }
        __syncthreads();
        // exclusive prefix scan of in-counts (hmem>>16) into loff16
        {
            const int lane = tid & 63, wid = tid >> 6;
            const int i0 = tid * 10;
            const int i1 = min(NNODES, i0 + 10);
            int s = 0;
            for (int i = i0; i < i1; ++i) s += (int)(((unsigned)hmem[i]) >> 16);
            int p = s;
#pragma unroll
            for (int d = 1; d < 64; d <<= 1) {
                int y = __shfl_up(p, d);
                if (lane >= d) p += y;
            }
            if (lane == 63) wsum[wid] = p;
            __syncthreads();
            if (tid < 16) {
                int v = wsum[tid];
#pragma unroll
                for (int d = 1; d < 16; d <<= 1) {
                    int y = __shfl_up(v, d);
                    if (tid >= d) v += y;
                }
                wsum[tid] = v;
            }
            __syncthreads();
            int run = (wid ? wsum[wid - 1] : 0) + (p - s);
            for (int i = i0; i < i1; ++i) {
                loff16[i] = (unsigned short)run;
                run += (int)(((unsigned)hmem[i]) >> 16);
            }
        }
        __syncthreads();
        // writeback meta (BLOCK-major: coalesced, line-exclusive) + outdeg
        for (int j = tid; j < NNODES; j += HBLOCK) {
            unsigned v = (unsigned)hmem[j];
            unsigned cnt = v >> 16;
            unsigned lo = (unsigned)loff16[j];
            meta[(size_t)b * NNODES + j] = lo | (cnt << 16);
            int od = (int)(v & 0xFFFFu);
            if (od) atomicAdd(&outdeg[j], od);
            hmem[j] = (int)lo;
        }
        __syncthreads();
        // pass2: bump-scatter src ids into block-private CSR region
        unsigned short* __restrict__ bc = blkcsr + (size_t)b * EPB;
        for (int qi = tid; qi < nq; qi += HBLOCK) {
            int4 r4 = r4p[qi], c4 = c4p[qi];
            int s0 = atomicAdd(&hmem[c4.x], 1);
            bc[s0] = (unsigned short)r4.x;
            int s1 = atomicAdd(&hmem[c4.y], 1);
            bc[s1] = (unsigned short)r4.y;
            int s2 = atomicAdd(&hmem[c4.z], 1);
            bc[s2] = (unsigned short)r4.z;
            int s3 = atomicAdd(&hmem[c4.w], 1);
            bc[s3] = (unsigned short)r4.w;
        }
        for (int e = e0 + nq * 4 + tid; e < e1; e += HBLOCK) {
            int slot = atomicAdd(&hmem[col[e]], 1);
            bc[slot] = (unsigned short)row[e];
        }
    } else {
        // ---- gemm: g = bf16(x @ W) unscaled; 128 rows/block, 4x4/thread --
        const int rowBase = (blockIdx.x - NB) * GROWS;
        // stage x-tile TRANSPOSED: xs[k*XPAD + r] = x[rowBase+r][k]
        {
            const float4* __restrict__ x4g = (const float4*)x;
#pragma unroll
            for (int i = 0; i < 4; ++i) {
                int idx = tid + i * HBLOCK;          // 4096 float4 slots
                int c16 = idx & 31;                  // k-group (4 k's)
                int r = idx >> 5;                    // row 0..127
                int gr = rowBase + r;
                float4 v = make_float4(0.f, 0.f, 0.f, 0.f);
                if (gr < N) v = x4g[(size_t)gr * 32 + c16];
                xs[(c16 * 4 + 0) * XPAD + r] = v.x;
                xs[(c16 * 4 + 1) * XPAD + r] = v.y;
                xs[(c16 * 4 + 2) * XPAD + r] = v.z;
                xs[(c16 * 4 + 3) * XPAD + r] = v.w;
            }
        }
        __syncthreads();
        // wave = 4 row-groups x 16 col-groups
        const int w = tid >> 6, lane = tid & 63;
        const int aa = w >> 1, bb = w & 1;
        const int rg = aa * 4 + (lane >> 4);         // 0..31 (4 rows each)
        const int c4 = bb * 16 + (lane & 15);        // 0..31 (4 cols each)
        const float4* __restrict__ W4 = (const float4*)W;
        float4 acc0 = make_float4(0.f, 0.f, 0.f, 0.f);
        float4 acc1 = make_float4(0.f, 0.f, 0.f, 0.f);
        float4 acc2 = make_float4(0.f, 0.f, 0.f, 0.f);
        float4 acc3 = make_float4(0.f, 0.f, 0.f, 0.f);
#pragma unroll 4
        for (int k = 0; k < 128; ++k) {
            float4 xv = *(const float4*)&xs[k * XPAD + rg * 4];  // 4 rows @ k
            float4 wv = W4[k * 32 + c4];                          // 4 cols @ k
            acc0.x = fmaf(xv.x, wv.x, acc0.x);
            acc0.y = fmaf(xv.x, wv.y, acc0.y);
            acc0.z = fmaf(xv.x, wv.z, acc0.z);
            acc0.w = fmaf(xv.x, wv.w, acc0.w);
            acc1.x = fmaf(xv.y, wv.x, acc1.x);
            acc1.y = fmaf(xv.y, wv.y, acc1.y);
            acc1.z = fmaf(xv.y, wv.z, acc1.z);
            acc1.w = fmaf(xv.y, wv.w, acc1.w);
            acc2.x = fmaf(xv.z, wv.x, acc2.x);
            acc2.y = fmaf(xv.z, wv.y, acc2.y);
            acc2.z = fmaf(xv.z, wv.z, acc2.z);
            acc2.w = fmaf(xv.z, wv.w, acc2.w);
            acc3.x = fmaf(xv.w, wv.x, acc3.x);
            acc3.y = fmaf(xv.w, wv.y, acc3.y);
            acc3.z = fmaf(xv.w, wv.z, acc3.z);
            acc3.w = fmaf(xv.w, wv.w, acc3.w);
        }
        ushort4* __restrict__ g4 = (ushort4*)g;
        const int r0 = rowBase + rg * 4;
        float4 accs[4] = { acc0, acc1, acc2, acc3 };
#pragma unroll
        for (int i = 0; i < 4; ++i) {
            int gr = r0 + i;
            if (gr < N) {
                ushort4 o;
                o.x = f2bf(accs[i].x);
                o.y = f2bf(accs[i].y);
                o.z = f2bf(accs[i].z);
                o.w = f2bf(accs[i].w);
                g4[(size_t)gr * 32 + c4] = o;
            }
        }
    }
}

// ---- K2: gather. Wave per node; lane l owns block l's CSR segment. ----
__global__ __launch_bounds__(256) void gather_kernel(
    const int* __restrict__ outdeg, const unsigned* __restrict__ meta,
    const unsigned short* __restrict__ blkcsr,
    const unsigned short* __restrict__ g, const float* __restrict__ bias,
    float* __restrict__ out, int N, int EPB) {
    __shared__ unsigned short stage[4][STAGE_CAP];
    __shared__ float dstage[4][STAGE_CAP];
    const int wv = threadIdx.x >> 6;
    const int lane = threadIdx.x & 63;
    const int c = (int)((blockIdx.x * blockDim.x + threadIdx.x) >> 6);
    const bool act = (c < N);

    // meta block-major: lane l reads meta[l*N + c] (strided, L2-hot)
    unsigned m = act ? meta[(size_t)lane * NNODES + c] : 0u;
    int sl = (int)(m & 0xFFFFu);
    int cn = (int)(m >> 16);
    // wave-exclusive prefix of segment counts -> flat position
    int p = cn;
#pragma unroll
    for (int d = 1; d < 64; d <<= 1) {
        int y = __shfl_up(p, d);
        if (lane >= d) p += y;
    }
    int excl = p - cn;
    int L = __shfl(p, 63);              // total indeg of node c
    // stage own segment (src id + ds) into the wave's flat LDS lists
    if (act && cn) {
        const unsigned short* seg = blkcsr + (size_t)lane * EPB + sl;
        for (int k = 0; k < cn; ++k) {
            int r = (int)seg[k];
            stage[wv][excl + k] = (unsigned short)r;
            dstage[wv][excl + k] = rsqrtf(1.0f + (float)outdeg[r]);
        }
    }
    __syncthreads();                     // arrival + LDS ordering
    if (!act) return;

    const int q = lane >> 4;             // edge sub-slot within a 4-edge step
    const int l16 = lane & 15;           // 16B chunk within the 256B row
    const uint4* __restrict__ g4 = (const uint4*)g;
    const float dc = rsqrtf(1.0f + (float)outdeg[c]);

    float al0 = 0.f, ah0 = 0.f, al1 = 0.f, ah1 = 0.f;
    float al2 = 0.f, ah2 = 0.f, al3 = 0.f, ah3 = 0.f;

    if (q == 0) {   // self-loop term: dis[c] * g[c] (counted once)
        uint4 w = g4[(size_t)c * 16 + l16];
        al0 = fmaf(bf2f_lo(w.x), dc, al0); ah0 = fmaf(bf2f_hi(w.x), dc, ah0);
        al1 = fmaf(bf2f_lo(w.y), dc, al1); ah1 = fmaf(bf2f_hi(w.y), dc, ah1);
        al2 = fmaf(bf2f_lo(w.z), dc, al2); ah2 = fmaf(bf2f_hi(w.z), dc, ah2);
        al3 = fmaf(bf2f_lo(w.w), dc, al3); ah3 = fmaf(bf2f_hi(w.w), dc, ah3);
    }

    for (int base = 0; base < L; base += 64) {
        int cnt = min(64, L - base);
#pragma unroll
        for (int t = 0; t < 64; t += 4) {
            int j = t + q;               // quarter q handles edge t+q
            if (j < cnt) {
                int r = (int)stage[wv][base + j];   // LDS broadcast
                float ds = dstage[wv][base + j];    // LDS broadcast
                uint4 w = g4[(size_t)r * 16 + l16];
                al0 = fmaf(bf2f_lo(w.x), ds, al0); ah0 = fmaf(bf2f_hi(w.x), ds, ah0);
                al1 = fmaf(bf2f_lo(w.y), ds, al1); ah1 = fmaf(bf2f_hi(w.y), ds, ah1);
                al2 = fmaf(bf2f_lo(w.z), ds, al2); ah2 = fmaf(bf2f_hi(w.z), ds, ah2);
                al3 = fmaf(bf2f_lo(w.w), ds, al3); ah3 = fmaf(bf2f_hi(w.w), ds, ah3);
            }
        }
    }
    // Butterfly over lane bits 5,4: full sums land in every lane.
    al0 += __shfl(al0, lane ^ 32); ah0 += __shfl(ah0, lane ^ 32);
    al1 += __shfl(al1, lane ^ 32); ah1 += __shfl(ah1, lane ^ 32);
    al2 += __shfl(al2, lane ^ 32); ah2 += __shfl(ah2, lane ^ 32);
    al3 += __shfl(al3, lane ^ 32); ah3 += __shfl(ah3, lane ^ 32);
    al0 += __shfl(al0, lane ^ 16); ah0 += __shfl(ah0, lane ^ 16);
    al1 += __shfl(al1, lane ^ 16); ah1 += __shfl(ah1, lane ^ 16);
    al2 += __shfl(al2, lane ^ 16); ah2 += __shfl(ah2, lane ^ 16);
    al3 += __shfl(al3, lane ^ 16); ah3 += __shfl(ah3, lane ^ 16);

    if (lane < 32) {
        int oi = ((lane & 15) << 1) | (lane >> 4);   // float4 slot 0..31
        float4 bv = ((const float4*)bias)[oi];
        float4 o;
        if (lane < 16) {
            o.x = fmaf(al0, dc, bv.x);
            o.y = fmaf(ah0, dc, bv.y);
            o.z = fmaf(al1, dc, bv.z);
            o.w = fmaf(ah1, dc, bv.w);
        } else {
            o.x = fmaf(al2, dc, bv.x);
            o.y = fmaf(ah2, dc, bv.y);
            o.z = fmaf(al3, dc, bv.z);
            o.w = fmaf(ah3, dc, bv.w);
        }
        ((float4*)out)[(size_t)c * 32 + oi] = o;
    }
}

extern "C" void kernel_launch(void* const* d_in, const int* in_sizes, int n_in,
                              void* d_out, int out_size, void* d_ws, size_t ws_size,
                              hipStream_t stream) {
    const float* x    = (const float*)d_in[0];
    const int*   ei   = (const int*)d_in[1];
    const float* W    = (const float*)d_in[2];
    const float* bias = (const float*)d_in[3];
    float* out = (float*)d_out;

    int N = in_sizes[0] / 128;     // 10000
    int E = in_sizes[1] / 2;       // 640000
    const int* row = ei;
    const int* col = ei + E;
    int EPB = (E + NB - 1) / NB;   // 10000

    // Workspace (~6.5 MB):
    auto align256 = [](size_t v) { return (v + 255) & ~(size_t)255; };
    char* p = (char*)d_ws;
    int*            outdeg = (int*)p;            p += align256((size_t)N * 4);           // 40 KB
    unsigned*       meta   = (unsigned*)p;       p += align256((size_t)NB * N * 4);      // 2.56 MB
    unsigned short* blkcsr = (unsigned short*)p; p += align256((size_t)NB * EPB * 2);    // 1.28 MB
    unsigned short* g      = (unsigned short*)p; p += align256((size_t)N * 128 * 2);     // 2.56 MB

    hipMemsetAsync(outdeg, 0, (size_t)N * 4, stream);

    int gemmBlocks = (N + GROWS - 1) / GROWS;   // 79
    histsort_gemm_kernel<<<NB + gemmBlocks, HBLOCK, 0, stream>>>(
        row, col, x, W, meta, outdeg, blkcsr, g, N, E, EPB);

    int gBlocks = (N + 3) / 4;       // 4 waves (nodes) per 256-thread block
    gather_kernel<<<gBlocks, 256, 0, stream>>>(
        outdeg, meta, blkcsr, g, bias, out, N, EPB);
}

// Round 11
// 105.755 us; speedup vs baseline: 1.1741x; 1.0316x over previous
//
#include <hip/hip_runtime.h>

// GCNConv: out = D^-1/2 (A + I) D^-1/2 (x W) + bias
// N = 10000, E = 640000, D_IN = D_OUT = 128, fp32 in/out.
//
// Round 18 (= R17 minus the suspect asm-barrier; R17 run died in infra):
//  1. GEMM x-tile staged ROW-major [128][33 float4] (float4 writes,
//     conflict-free; R16's transposed staging was a computed 16-way LDS
//     bank conflict). Inner loop reads 4 rows x 4 k via ds_read_b128
//     along k (row stride 132 dwords = 2-way conflict = free).
//     FMA order per output unchanged -> g bit-identical to R16.
//  2. K2 keeps the R16-verified __syncthreads() (R17's wave-local
//     s_waitcnt replacement is parked until infra vs kernel is resolved).
// Structure (R13..R16-verified): memset(outdeg) -> K1 histsort||gemm -> K2.

#define NNODES 10000
#define NB 64            // hist blocks == CSR buckets == gather lanes
#define HBLOCK 1024
#define STAGE_CAP 256    // max indeg staged per wave (obs max ~110)
#define GROWS 128        // gemm rows per block
#define XPAD 132         // row stride (dwords) of row-major x-tile (33 float4)

__device__ inline unsigned short f2bf(float f) {
    union { float f; unsigned u; } v; v.f = f;
    unsigned r = v.u + 0x7FFFu + ((v.u >> 16) & 1u);   // RNE
    return (unsigned short)(r >> 16);
}
__device__ inline float bf2f_lo(unsigned u) {   // low ushort of dword -> f32
    union { unsigned u; float f; } v; v.u = u << 16; return v.f;
}
__device__ inline float bf2f_hi(unsigned u) {   // high ushort of dword -> f32
    union { unsigned u; float f; } v; v.u = u & 0xFFFF0000u; return v.f;
}

// ---- K1: blocks 0..NB-1 hist-sort; blocks NB.. gemm (unscaled bf16) ----
__global__ __launch_bounds__(HBLOCK) void histsort_gemm_kernel(
    const int* __restrict__ row, const int* __restrict__ col,
    const float* __restrict__ x, const float* __restrict__ W,
    unsigned* __restrict__ meta, int* __restrict__ outdeg,
    unsigned short* __restrict__ blkcsr, unsigned short* __restrict__ g,
    int N, int E, int EPB) {
    // union: hist needs 60.1 KB; gemm x-tile 128*132*4 = 67.6 KB.
    __shared__ __align__(16) char smem[GROWS * XPAD * 4];
    int* hmem = (int*)smem;                               // [NNODES]
    unsigned short* loff16 = (unsigned short*)(smem + 40000);  // [NNODES]
    int* wsum = (int*)(smem + 60000);                     // [16]
    float* xs = (float*)smem;                             // [128][XPAD]
    const int tid = threadIdx.x;

    if (blockIdx.x < NB) {
        const int b = blockIdx.x;
        for (int j = tid; j < NNODES; j += HBLOCK) hmem[j] = 0;
        __syncthreads();
        const int e0 = b * EPB, e1 = min(E, e0 + EPB);
        const int span = e1 - e0;
        const bool vec4 = ((((size_t)(row + e0)) | ((size_t)(col + e0))) & 15) == 0;
        const int nq = vec4 ? (span >> 2) : 0;
        const int4* __restrict__ r4p = (const int4*)(row + e0);
        const int4* __restrict__ c4p = (const int4*)(col + e0);
        // pass1: packed counts (out lo16 | in hi16)
        for (int qi = tid; qi < nq; qi += HBLOCK) {
            int4 r4 = r4p[qi], c4 = c4p[qi];
            atomicAdd((unsigned*)&hmem[r4.x], 1u);
            atomicAdd((unsigned*)&hmem[r4.y], 1u);
            atomicAdd((unsigned*)&hmem[r4.z], 1u);
            atomicAdd((unsigned*)&hmem[r4.w], 1u);
            atomicAdd((unsigned*)&hmem[c4.x], 0x10000u);
            atomicAdd((unsigned*)&hmem[c4.y], 0x10000u);
            atomicAdd((unsigned*)&hmem[c4.z], 0x10000u);
            atomicAdd((unsigned*)&hmem[c4.w], 0x10000u);
        }
        for (int e = e0 + nq * 4 + tid; e < e1; e += HBLOCK) {
            atomicAdd((unsigned*)&hmem[row[e]], 1u);
            atomicAdd((unsigned*)&hmem[col[e]], 0x10000u);
        }
        __syncthreads();
        // exclusive prefix scan of in-counts (hmem>>16) into loff16
        {
            const int lane = tid & 63, wid = tid >> 6;
            const int i0 = tid * 10;
            const int i1 = min(NNODES, i0 + 10);
            int s = 0;
            for (int i = i0; i < i1; ++i) s += (int)(((unsigned)hmem[i]) >> 16);
            int p = s;
#pragma unroll
            for (int d = 1; d < 64; d <<= 1) {
                int y = __shfl_up(p, d);
                if (lane >= d) p += y;
            }
            if (lane == 63) wsum[wid] = p;
            __syncthreads();
            if (tid < 16) {
                int v = wsum[tid];
#pragma unroll
                for (int d = 1; d < 16; d <<= 1) {
                    int y = __shfl_up(v, d);
                    if (tid >= d) v += y;
                }
                wsum[tid] = v;
            }
            __syncthreads();
            int run = (wid ? wsum[wid - 1] : 0) + (p - s);
            for (int i = i0; i < i1; ++i) {
                loff16[i] = (unsigned short)run;
                run += (int)(((unsigned)hmem[i]) >> 16);
            }
        }
        __syncthreads();
        // writeback meta (BLOCK-major: coalesced, line-exclusive) + outdeg
        for (int j = tid; j < NNODES; j += HBLOCK) {
            unsigned v = (unsigned)hmem[j];
            unsigned cnt = v >> 16;
            unsigned lo = (unsigned)loff16[j];
            meta[(size_t)b * NNODES + j] = lo | (cnt << 16);
            int od = (int)(v & 0xFFFFu);
            if (od) atomicAdd(&outdeg[j], od);
            hmem[j] = (int)lo;
        }
        __syncthreads();
        // pass2: bump-scatter src ids into block-private CSR region
        unsigned short* __restrict__ bc = blkcsr + (size_t)b * EPB;
        for (int qi = tid; qi < nq; qi += HBLOCK) {
            int4 r4 = r4p[qi], c4 = c4p[qi];
            int s0 = atomicAdd(&hmem[c4.x], 1);
            bc[s0] = (unsigned short)r4.x;
            int s1 = atomicAdd(&hmem[c4.y], 1);
            bc[s1] = (unsigned short)r4.y;
            int s2 = atomicAdd(&hmem[c4.z], 1);
            bc[s2] = (unsigned short)r4.z;
            int s3 = atomicAdd(&hmem[c4.w], 1);
            bc[s3] = (unsigned short)r4.w;
        }
        for (int e = e0 + nq * 4 + tid; e < e1; e += HBLOCK) {
            int slot = atomicAdd(&hmem[col[e]], 1);
            bc[slot] = (unsigned short)row[e];
        }
    } else {
        // ---- gemm: g = bf16(x @ W) unscaled; 128 rows/block, 4x4/thread --
        const int rowBase = (blockIdx.x - NB) * GROWS;
        // stage x-tile ROW-major: xs4[r*33 + c16] (float4 writes: coalesced
        // global, conflict-free LDS)
        {
            const float4* __restrict__ x4g = (const float4*)x;
            float4* __restrict__ xs4 = (float4*)xs;
#pragma unroll
            for (int i = 0; i < 4; ++i) {
                int idx = tid + i * HBLOCK;          // 4096 float4 slots
                int c16 = idx & 31;                  // k-group (4 k's)
                int r = idx >> 5;                    // row 0..127
                int gr = rowBase + r;
                float4 v = make_float4(0.f, 0.f, 0.f, 0.f);
                if (gr < N) v = x4g[(size_t)gr * 32 + c16];
                xs4[r * 33 + c16] = v;
            }
        }
        __syncthreads();
        // wave = 4 row-groups x 16 col-groups
        const int w = tid >> 6, lane = tid & 63;
        const int aa = w >> 1, bb = w & 1;
        const int rg = aa * 4 + (lane >> 4);         // 0..31 (4 rows each)
        const int c4 = bb * 16 + (lane & 15);        // 0..31 (4 cols each)
        const float4* __restrict__ W4 = (const float4*)W;
        const float* __restrict__ xr0 = xs + (rg * 4 + 0) * XPAD;
        const float* __restrict__ xr1 = xs + (rg * 4 + 1) * XPAD;
        const float* __restrict__ xr2 = xs + (rg * 4 + 2) * XPAD;
        const float* __restrict__ xr3 = xs + (rg * 4 + 3) * XPAD;
        float4 acc0 = make_float4(0.f, 0.f, 0.f, 0.f);
        float4 acc1 = make_float4(0.f, 0.f, 0.f, 0.f);
        float4 acc2 = make_float4(0.f, 0.f, 0.f, 0.f);
        float4 acc3 = make_float4(0.f, 0.f, 0.f, 0.f);
#pragma unroll 2
        for (int k0 = 0; k0 < 128; k0 += 4) {
            float4 a0 = *(const float4*)(xr0 + k0);   // rows' k0..k0+3
            float4 a1 = *(const float4*)(xr1 + k0);
            float4 a2 = *(const float4*)(xr2 + k0);
            float4 a3 = *(const float4*)(xr3 + k0);
#pragma unroll
            for (int j = 0; j < 4; ++j) {
                float4 wv = W4[(k0 + j) * 32 + c4];
                float x0 = ((const float*)&a0)[j];
                float x1 = ((const float*)&a1)[j];
                float x2 = ((const float*)&a2)[j];
                float x3 = ((const float*)&a3)[j];
                acc0.x = fmaf(x0, wv.x, acc0.x);
                acc0.y = fmaf(x0, wv.y, acc0.y);
                acc0.z = fmaf(x0, wv.z, acc0.z);
                acc0.w = fmaf(x0, wv.w, acc0.w);
                acc1.x = fmaf(x1, wv.x, acc1.x);
                acc1.y = fmaf(x1, wv.y, acc1.y);
                acc1.z = fmaf(x1, wv.z, acc1.z);
                acc1.w = fmaf(x1, wv.w, acc1.w);
                acc2.x = fmaf(x2, wv.x, acc2.x);
                acc2.y = fmaf(x2, wv.y, acc2.y);
                acc2.z = fmaf(x2, wv.z, acc2.z);
                acc2.w = fmaf(x2, wv.w, acc2.w);
                acc3.x = fmaf(x3, wv.x, acc3.x);
                acc3.y = fmaf(x3, wv.y, acc3.y);
                acc3.z = fmaf(x3, wv.z, acc3.z);
                acc3.w = fmaf(x3, wv.w, acc3.w);
            }
        }
        ushort4* __restrict__ g4 = (ushort4*)g;
        const int r0 = rowBase + rg * 4;
        float4 accs[4] = { acc0, acc1, acc2, acc3 };
#pragma unroll
        for (int i = 0; i < 4; ++i) {
            int gr = r0 + i;
            if (gr < N) {
                ushort4 o;
                o.x = f2bf(accs[i].x);
                o.y = f2bf(accs[i].y);
                o.z = f2bf(accs[i].z);
                o.w = f2bf(accs[i].w);
                g4[(size_t)gr * 32 + c4] = o;
            }
        }
    }
}

// ---- K2: gather. Wave per node; lane l owns block l's CSR segment. ----
__global__ __launch_bounds__(256) void gather_kernel(
    const int* __restrict__ outdeg, const unsigned* __restrict__ meta,
    const unsigned short* __restrict__ blkcsr,
    const unsigned short* __restrict__ g, const float* __restrict__ bias,
    float* __restrict__ out, int N, int EPB) {
    __shared__ unsigned short stage[4][STAGE_CAP];
    __shared__ float dstage[4][STAGE_CAP];
    const int wv = threadIdx.x >> 6;
    const int lane = threadIdx.x & 63;
    const int c = (int)((blockIdx.x * blockDim.x + threadIdx.x) >> 6);
    const bool act = (c < N);

    // meta block-major: lane l reads meta[l*N + c] (strided, L2-hot)
    unsigned m = act ? meta[(size_t)lane * NNODES + c] : 0u;
    int sl = (int)(m & 0xFFFFu);
    int cn = (int)(m >> 16);
    // wave-exclusive prefix of segment counts -> flat position
    int p = cn;
#pragma unroll
    for (int d = 1; d < 64; d <<= 1) {
        int y = __shfl_up(p, d);
        if (lane >= d) p += y;
    }
    int excl = p - cn;
    int L = __shfl(p, 63);              // total indeg of node c
    // stage own segment (src id + ds) into the wave's flat LDS lists
    if (act && cn) {
        const unsigned short* seg = blkcsr + (size_t)lane * EPB + sl;
        for (int k = 0; k < cn; ++k) {
            int r = (int)seg[k];
            stage[wv][excl + k] = (unsigned short)r;
            dstage[wv][excl + k] = rsqrtf(1.0f + (float)outdeg[r]);
        }
    }
    __syncthreads();                     // arrival + LDS ordering (verified)
    if (!act) return;

    const int q = lane >> 4;             // edge sub-slot within a 4-edge step
    const int l16 = lane & 15;           // 16B chunk within the 256B row
    const uint4* __restrict__ g4 = (const uint4*)g;
    const float dc = rsqrtf(1.0f + (float)outdeg[c]);

    float al0 = 0.f, ah0 = 0.f, al1 = 0.f, ah1 = 0.f;
    float al2 = 0.f, ah2 = 0.f, al3 = 0.f, ah3 = 0.f;

    if (q == 0) {   // self-loop term: dis[c] * g[c] (counted once)
        uint4 w = g4[(size_t)c * 16 + l16];
        al0 = fmaf(bf2f_lo(w.x), dc, al0); ah0 = fmaf(bf2f_hi(w.x), dc, ah0);
        al1 = fmaf(bf2f_lo(w.y), dc, al1); ah1 = fmaf(bf2f_hi(w.y), dc, ah1);
        al2 = fmaf(bf2f_lo(w.z), dc, al2); ah2 = fmaf(bf2f_hi(w.z), dc, ah2);
        al3 = fmaf(bf2f_lo(w.w), dc, al3); ah3 = fmaf(bf2f_hi(w.w), dc, ah3);
    }

    for (int base = 0; base < L; base += 64) {
        int cnt = min(64, L - base);
#pragma unroll
        for (int t = 0; t < 64; t += 4) {
            int j = t + q;               // quarter q handles edge t+q
            if (j < cnt) {
                int r = (int)stage[wv][base + j];   // LDS broadcast
                float ds = dstage[wv][base + j];    // LDS broadcast
                uint4 w = g4[(size_t)r * 16 + l16];
                al0 = fmaf(bf2f_lo(w.x), ds, al0); ah0 = fmaf(bf2f_hi(w.x), ds, ah0);
                al1 = fmaf(bf2f_lo(w.y), ds, al1); ah1 = fmaf(bf2f_hi(w.y), ds, ah1);
                al2 = fmaf(bf2f_lo(w.z), ds, al2); ah2 = fmaf(bf2f_hi(w.z), ds, ah2);
                al3 = fmaf(bf2f_lo(w.w), ds, al3); ah3 = fmaf(bf2f_hi(w.w), ds, ah3);
            }
        }
    }
    // Butterfly over lane bits 5,4: full sums land in every lane.
    al0 += __shfl(al0, lane ^ 32); ah0 += __shfl(ah0, lane ^ 32);
    al1 += __shfl(al1, lane ^ 32); ah1 += __shfl(ah1, lane ^ 32);
    al2 += __shfl(al2, lane ^ 32); ah2 += __shfl(ah2, lane ^ 32);
    al3 += __shfl(al3, lane ^ 32); ah3 += __shfl(ah3, lane ^ 32);
    al0 += __shfl(al0, lane ^ 16); ah0 += __shfl(ah0, lane ^ 16);
    al1 += __shfl(al1, lane ^ 16); ah1 += __shfl(ah1, lane ^ 16);
    al2 += __shfl(al2, lane ^ 16); ah2 += __shfl(ah2, lane ^ 16);
    al3 += __shfl(al3, lane ^ 16); ah3 += __shfl(ah3, lane ^ 16);

    if (lane < 32) {
        int oi = ((lane & 15) << 1) | (lane >> 4);   // float4 slot 0..31
        float4 bv = ((const float4*)bias)[oi];
        float4 o;
        if (lane < 16) {
            o.x = fmaf(al0, dc, bv.x);
            o.y = fmaf(ah0, dc, bv.y);
            o.z = fmaf(al1, dc, bv.z);
            o.w = fmaf(ah1, dc, bv.w);
        } else {
            o.x = fmaf(al2, dc, bv.x);
            o.y = fmaf(ah2, dc, bv.y);
            o.z = fmaf(al3, dc, bv.z);
            o.w = fmaf(ah3, dc, bv.w);
        }
        ((float4*)out)[(size_t)c * 32 + oi] = o;
    }
}

extern "C" void kernel_launch(void* const* d_in, const int* in_sizes, int n_in,
                              void* d_out, int out_size, void* d_ws, size_t ws_size,
                              hipStream_t stream) {
    const float* x    = (const float*)d_in[0];
    const int*   ei   = (const int*)d_in[1];
    const float* W    = (const float*)d_in[2];
    const float* bias = (const float*)d_in[3];
    float* out = (float*)d_out;

    int N = in_sizes[0] / 128;     // 10000
    int E = in_sizes[1] / 2;       // 640000
    const int* row = ei;
    const int* col = ei + E;
    int EPB = (E + NB - 1) / NB;   // 10000

    // Workspace (~6.5 MB):
    auto align256 = [](size_t v) { return (v + 255) & ~(size_t)255; };
    char* p = (char*)d_ws;
    int*            outdeg = (int*)p;            p += align256((size_t)N * 4);           // 40 KB
    unsigned*       meta   = (unsigned*)p;       p += align256((size_t)NB * N * 4);      // 2.56 MB
    unsigned short* blkcsr = (unsigned short*)p; p += align256((size_t)NB * EPB * 2);    // 1.28 MB
    unsigned short* g      = (unsigned short*)p; p += align256((size_t)N * 128 * 2);     // 2.56 MB

    hipMemsetAsync(outdeg, 0, (size_t)N * 4, stream);

    int gemmBlocks = (N + GROWS - 1) / GROWS;   // 79
    histsort_gemm_kernel<<<NB + gemmBlocks, HBLOCK, 0, stream>>>(
        row, col, x, W, meta, outdeg, blkcsr, g, N, E, EPB);

    int gBlocks = (N + 3) / 4;       // 4 waves (nodes) per 256-thread block
    gather_kernel<<<gBlocks, 256, 0, stream>>>(
        outdeg, meta, blkcsr, g, bias, out, N, EPB);
}